// Round 1
// baseline (1686.021 us; speedup 1.0000x reference)
//
#include <hip/hip_runtime.h>
#include <hip/hip_bf16.h>

typedef __attribute__((ext_vector_type(4))) float f32x4;
typedef __attribute__((ext_vector_type(8))) short short8;
typedef __attribute__((ext_vector_type(4))) unsigned short u16x4;

#define M_ROWS 12544   // 16*28*28
#define N_MEM  16384
#define K_DIM  1536

__device__ __forceinline__ float bf2f(unsigned short u) {
  return __uint_as_float(((unsigned)u) << 16);
}
__device__ __forceinline__ unsigned short f2bf(float f) {
  unsigned u = __float_as_uint(f);
  u += 0x7FFF + ((u >> 16) & 1);   // RNE
  return (unsigned short)(u >> 16);
}

// ---------------- Kernel 1: build embedding (avg_pool3 + upsample + concat) as bf16
__global__ __launch_bounds__(256) void emb_kernel(
    const float* __restrict__ f2, const float* __restrict__ f3,
    unsigned short* __restrict__ emb)
{
  int gid = blockIdx.x * 256 + threadIdx.x;      // 12544*1536 threads
  int r = gid / K_DIM;
  int c = gid - r * K_DIM;
  int b = r / 784;
  int s = r - b * 784;
  int h = s / 28;
  int w = s - h * 28;
  float v = 0.f;
  if (c < 512) {
    const float* plane = f2 + ((size_t)b * 512 + c) * 784;
    for (int dh = -1; dh <= 1; ++dh) {
      int hh = h + dh; if (hh < 0 || hh > 27) continue;
      for (int dw = -1; dw <= 1; ++dw) {
        int ww = w + dw; if (ww < 0 || ww > 27) continue;
        v += plane[hh * 28 + ww];
      }
    }
  } else {
    int c3 = c - 512;
    int h3 = h >> 1, w3 = w >> 1;
    const float* plane = f3 + ((size_t)b * 1024 + c3) * 196;
    for (int dh = -1; dh <= 1; ++dh) {
      int hh = h3 + dh; if (hh < 0 || hh > 13) continue;
      for (int dw = -1; dw <= 1; ++dw) {
        int ww = w3 + dw; if (ww < 0 || ww > 13) continue;
        v += plane[hh * 14 + ww];
      }
    }
  }
  emb[gid] = f2bf(v * (1.f / 9.f));
}

// ---------------- Kernel 2: memory_bank -> bf16 + m2 (row sum of squares)
__global__ __launch_bounds__(256) void mbconv_kernel(
    const float* __restrict__ mb, unsigned short* __restrict__ mbb,
    float* __restrict__ m2)
{
  int wave = threadIdx.x >> 6, lane = threadIdx.x & 63;
  int row = blockIdx.x * 4 + wave;
  const float* src = mb + (size_t)row * K_DIM;
  unsigned short* dst = mbb + (size_t)row * K_DIM;
  float s = 0.f;
  #pragma unroll
  for (int c = 0; c < 6; ++c) {
    int off = c * 256 + lane * 4;
    float4 v = *(const float4*)(src + off);
    s += v.x * v.x + v.y * v.y + v.z * v.z + v.w * v.w;
    u16x4 o; o[0] = f2bf(v.x); o[1] = f2bf(v.y); o[2] = f2bf(v.z); o[3] = f2bf(v.w);
    *(u16x4*)(dst + off) = o;
  }
  #pragma unroll
  for (int d = 1; d < 64; d <<= 1) s += __shfl_xor(s, d);
  if (lane == 0) m2[row] = s;
}

// ---------------- Kernel 3: x2 (row sum of squares of bf16 embedding)
__global__ __launch_bounds__(256) void x2_kernel(
    const unsigned short* __restrict__ emb, float* __restrict__ x2)
{
  int wave = threadIdx.x >> 6, lane = threadIdx.x & 63;
  int row = blockIdx.x * 4 + wave;
  const unsigned short* src = emb + (size_t)row * K_DIM;
  float s = 0.f;
  #pragma unroll
  for (int c = 0; c < 3; ++c) {
    short8 v = *(const short8*)(src + c * 512 + lane * 8);
    #pragma unroll
    for (int j = 0; j < 8; ++j) {
      float f = bf2f((unsigned short)v[j]);
      s += f * f;
    }
  }
  #pragma unroll
  for (int d = 1; d < 64; d <<= 1) s += __shfl_xor(s, d);
  if (lane == 0) x2[row] = s;
}

// ---------------- Kernel 4: fused GEMM + min over columns
// grid: (N_MEM/128, M_ROWS/128) = (128, 98), block 256 (4 waves, 2x2)
// partial[r*256 + bn*2 + wc] = min over that block-half's 64 columns of (m2[m] - 2*dot)
__global__ __launch_bounds__(256) void gemm_min_kernel(
    const unsigned short* __restrict__ A,   // emb bf16 [12544][1536]
    const unsigned short* __restrict__ Bm,  // mb  bf16 [16384][1536]
    const float* __restrict__ m2,
    float* __restrict__ partial)
{
  __shared__ unsigned short lA[128 * 32];
  __shared__ unsigned short lB[128 * 32];
  const int tid = threadIdx.x;
  const int wave = tid >> 6, lane = tid & 63;
  const int bn = blockIdx.x, bm = blockIdx.y;
  const int rowBase = bm * 128, colBase = bn * 128;
  const int wr = wave >> 1, wc = wave & 1;

  f32x4 acc[4][4];
  #pragma unroll
  for (int i = 0; i < 4; ++i)
    #pragma unroll
    for (int j = 0; j < 4; ++j)
      acc[i][j] = (f32x4){0.f, 0.f, 0.f, 0.f};

  for (int kk = 0; kk < K_DIM; kk += 32) {
    // stage A and B tiles: 8KB each, 2 rounds of 256 lanes * 16B
    #pragma unroll
    for (int i = 0; i < 2; ++i) {
      int e = i * 2048 + wave * 512 + lane * 8;     // element offset in tile
      int trow = e >> 5, tcol = e & 31;
      __builtin_amdgcn_global_load_lds(
          (const __attribute__((address_space(1))) void*)(A + (size_t)(rowBase + trow) * K_DIM + kk + tcol),
          (__attribute__((address_space(3))) void*)(lA + i * 2048 + wave * 512), 16, 0, 0);
      __builtin_amdgcn_global_load_lds(
          (const __attribute__((address_space(1))) void*)(Bm + (size_t)(colBase + trow) * K_DIM + kk + tcol),
          (__attribute__((address_space(3))) void*)(lB + i * 2048 + wave * 512), 16, 0, 0);
    }
    __syncthreads();
    short8 af[4], bf[4];
    #pragma unroll
    for (int f = 0; f < 4; ++f) {
      af[f] = *reinterpret_cast<const short8*>(&lA[(wr * 64 + f * 16 + (lane & 15)) * 32 + (lane >> 4) * 8]);
      bf[f] = *reinterpret_cast<const short8*>(&lB[(wc * 64 + f * 16 + (lane & 15)) * 32 + (lane >> 4) * 8]);
    }
    #pragma unroll
    for (int i = 0; i < 4; ++i)
      #pragma unroll
      for (int j = 0; j < 4; ++j)
        acc[i][j] = __builtin_amdgcn_mfma_f32_16x16x32_bf16(af[i], bf[j], acc[i][j], 0, 0, 0);
    __syncthreads();
  }

  // epilogue: val = m2[m] - 2*dot ; min over wave's 64 columns; store per row
  float m2v[4];
  #pragma unroll
  for (int j = 0; j < 4; ++j)
    m2v[j] = m2[colBase + wc * 64 + j * 16 + (lane & 15)];
  const int q = lane >> 4;
  #pragma unroll
  for (int i = 0; i < 4; ++i) {
    #pragma unroll
    for (int v = 0; v < 4; ++v) {
      float mn = fminf(fminf(m2v[0] - 2.f * acc[i][0][v], m2v[1] - 2.f * acc[i][1][v]),
                       fminf(m2v[2] - 2.f * acc[i][2][v], m2v[3] - 2.f * acc[i][3][v]));
      #pragma unroll
      for (int d = 1; d < 16; d <<= 1) mn = fminf(mn, __shfl_xor(mn, d));
      if ((lane & 15) == 0) {
        int r = rowBase + wr * 64 + i * 16 + q * 4 + v;
        partial[(size_t)r * 256 + bn * 2 + wc] = mn;
      }
    }
  }
}

// ---------------- Kernel 5: reduce 256 partials per row -> s0 = sqrt(max(x2+min,eps))
__global__ __launch_bounds__(256) void reduce_min_kernel(
    const float* __restrict__ partial, const float* __restrict__ x2,
    float* __restrict__ s0)
{
  int wave = threadIdx.x >> 6, lane = threadIdx.x & 63;
  int r = blockIdx.x * 4 + wave;
  float4 v4 = *(const float4*)&partial[(size_t)r * 256 + lane * 4];
  float mn = fminf(fminf(v4.x, v4.y), fminf(v4.z, v4.w));
  #pragma unroll
  for (int d = 1; d < 64; d <<= 1) mn = fminf(mn, __shfl_xor(mn, d));
  if (lane == 0) s0[r] = sqrtf(fmaxf(x2[r] + mn, 1e-12f));
}

// ---------------- Kernel 6: argmax over s0
__global__ __launch_bounds__(256) void argmax_kernel(
    const float* __restrict__ s0, float* __restrict__ scal)
{
  __shared__ float sv[256];
  __shared__ int si[256];
  int tid = threadIdx.x;
  float best = -1e30f; int bi = 0x7fffffff;
  for (int i = tid; i < M_ROWS; i += 256) {
    float v = s0[i];
    if (v > best) { best = v; bi = i; }
  }
  sv[tid] = best; si[tid] = bi;
  __syncthreads();
  for (int s = 128; s > 0; s >>= 1) {
    if (tid < s) {
      if (sv[tid + s] > sv[tid] || (sv[tid + s] == sv[tid] && si[tid + s] < si[tid])) {
        sv[tid] = sv[tid + s]; si[tid] = si[tid + s];
      }
    }
    __syncthreads();
  }
  if (tid == 0) { scal[0] = sv[0]; ((int*)scal)[1] = si[0]; }
}

// ---------------- Kernel 7: distances of the argmax row to all memory entries
__global__ __launch_bounds__(256) void rowdist_kernel(
    const unsigned short* __restrict__ emb, const unsigned short* __restrict__ mbb,
    const float* __restrict__ x2, const float* __restrict__ m2,
    const float* __restrict__ scal, float* __restrict__ dists)
{
  int wave = threadIdx.x >> 6, lane = threadIdx.x & 63;
  int m = blockIdx.x * 4 + wave;
  int ridx = ((const int*)scal)[1];
  const unsigned short* er = emb + (size_t)ridx * K_DIM;
  const unsigned short* mr = mbb + (size_t)m * K_DIM;
  float dot = 0.f;
  #pragma unroll
  for (int c = 0; c < 3; ++c) {
    short8 a = *(const short8*)(er + c * 512 + lane * 8);
    short8 b = *(const short8*)(mr + c * 512 + lane * 8);
    #pragma unroll
    for (int j = 0; j < 8; ++j)
      dot += bf2f((unsigned short)a[j]) * bf2f((unsigned short)b[j]);
  }
  #pragma unroll
  for (int d = 1; d < 64; d <<= 1) dot += __shfl_xor(dot, d);
  if (lane == 0)
    dists[m] = sqrtf(fmaxf(x2[ridx] + m2[m] - 2.f * dot, 1e-12f));
}

// ---------------- Kernel 8: top-9 smallest dists -> weights -> anomaly_score
__global__ __launch_bounds__(256) void topk_kernel(
    const float* __restrict__ dists, const float* __restrict__ scal,
    float* __restrict__ out)
{
  __shared__ float conf[9];
  __shared__ int chosen[9];
  __shared__ float swv[4];
  __shared__ int swi[4];
  int tid = threadIdx.x, lane = tid & 63, wave = tid >> 6;
  for (int t = 0; t < 9; ++t) {
    float best = 1e30f; int bi = 0x7fffffff;
    for (int i = tid; i < N_MEM; i += 256) {
      bool skip = false;
      for (int u = 0; u < t; ++u) skip = skip || (chosen[u] == i);
      if (skip) continue;
      float v = dists[i];
      if (v < best || (v == best && i < bi)) { best = v; bi = i; }
    }
    #pragma unroll
    for (int d = 1; d < 64; d <<= 1) {
      float ov = __shfl_xor(best, d); int oi = __shfl_xor(bi, d);
      if (ov < best || (ov == best && oi < bi)) { best = ov; bi = oi; }
    }
    if (lane == 0) { swv[wave] = best; swi[wave] = bi; }
    __syncthreads();
    if (tid == 0) {
      float bb = swv[0]; int bbi = swi[0];
      for (int w = 1; w < 4; ++w)
        if (swv[w] < bb || (swv[w] == bb && swi[w] < bbi)) { bb = swv[w]; bbi = swi[w]; }
      conf[t] = bb; chosen[t] = bbi;
    }
    __syncthreads();
  }
  if (tid == 0) {
    float me = conf[0];
    for (int i = 1; i < 9; ++i) me = fmaxf(me, conf[i]);
    float den = 0.f;
    for (int i = 0; i < 9; ++i) den += expf(conf[i] - me);
    float w = 1.f - 1.f / den;
    out[802816] = w * scal[0];
  }
}

// ---------------- Kernels 9/10: 8x upsample + separable 33-tap gaussian blur (reflect)
__global__ __launch_bounds__(256) void blurV_kernel(
    const float* __restrict__ s0, float* __restrict__ tmp)
{
  __shared__ float g[33];
  __shared__ float ginv;
  int tid = threadIdx.x;
  if (tid < 33) { float x = (tid - 16) * 0.25f; g[tid] = expf(-0.5f * x * x); }
  __syncthreads();
  if (tid == 0) { float s = 0.f; for (int i = 0; i < 33; ++i) s += g[i]; ginv = 1.f / s; }
  __syncthreads();
  int gid = blockIdx.x * 256 + tid;       // 16*224*224
  int b = gid / 50176;
  int rem = gid - b * 50176;
  int y = rem / 224, x = rem - (rem / 224) * 224;
  const float* sb = s0 + b * 784;
  int sx = x >> 3;
  float acc = 0.f;
  for (int k = 0; k < 33; ++k) {
    int yy = y + k - 16;
    yy = (yy < 0) ? -yy : yy;
    yy = (yy > 223) ? 446 - yy : yy;
    acc += g[k] * sb[(yy >> 3) * 28 + sx];
  }
  tmp[gid] = acc * ginv;
}

__global__ __launch_bounds__(256) void blurH_kernel(
    const float* __restrict__ tmp, float* __restrict__ out)
{
  __shared__ float g[33];
  __shared__ float ginv;
  int tid = threadIdx.x;
  if (tid < 33) { float x = (tid - 16) * 0.25f; g[tid] = expf(-0.5f * x * x); }
  __syncthreads();
  if (tid == 0) { float s = 0.f; for (int i = 0; i < 33; ++i) s += g[i]; ginv = 1.f / s; }
  __syncthreads();
  int gid = blockIdx.x * 256 + tid;
  int b = gid / 50176;
  int rem = gid - b * 50176;
  int y = rem / 224, x = rem - (rem / 224) * 224;
  const float* tb = tmp + b * 50176 + y * 224;
  float acc = 0.f;
  for (int k = 0; k < 33; ++k) {
    int xx = x + k - 16;
    xx = (xx < 0) ? -xx : xx;
    xx = (xx > 223) ? 446 - xx : xx;
    acc += g[k] * tb[xx];
  }
  out[gid] = acc * ginv;
}

extern "C" void kernel_launch(void* const* d_in, const int* in_sizes, int n_in,
                              void* d_out, int out_size, void* d_ws, size_t ws_size,
                              hipStream_t stream) {
  const float* f2 = (const float*)d_in[0];
  const float* f3 = (const float*)d_in[1];
  const float* mb = (const float*)d_in[2];
  float* out = (float*)d_out;
  char* ws = (char*)d_ws;

  unsigned short* emb = (unsigned short*)(ws + 0);            // 38,535,168 B
  unsigned short* mbb = (unsigned short*)(ws + 38535168);     // 50,331,648 B
  float* x2      = (float*)(ws + 88866816);                   // 50,176 B
  float* m2      = (float*)(ws + 88916992);                   // 65,536 B
  float* partial = (float*)(ws + 88982528);                   // 12,845,056 B
  float* s0      = (float*)(ws + 101827584);                  // 50,176 B
  float* scal    = (float*)(ws + 101877760);                  // 64 B
  float* dists   = (float*)(ws + 101877824);                  // 65,536 B
  float* tmp     = (float*)(ws + 101943360);                  // 3,211,264 B

  hipLaunchKernelGGL(emb_kernel, dim3(75264), dim3(256), 0, stream, f2, f3, emb);
  hipLaunchKernelGGL(mbconv_kernel, dim3(4096), dim3(256), 0, stream, mb, mbb, m2);
  hipLaunchKernelGGL(x2_kernel, dim3(3136), dim3(256), 0, stream, emb, x2);
  hipLaunchKernelGGL(gemm_min_kernel, dim3(128, 98), dim3(256), 0, stream, emb, mbb, m2, partial);
  hipLaunchKernelGGL(reduce_min_kernel, dim3(3136), dim3(256), 0, stream, partial, x2, s0);
  hipLaunchKernelGGL(argmax_kernel, dim3(1), dim3(256), 0, stream, s0, scal);
  hipLaunchKernelGGL(rowdist_kernel, dim3(4096), dim3(256), 0, stream, emb, mbb, x2, m2, scal, dists);
  hipLaunchKernelGGL(topk_kernel, dim3(1), dim3(256), 0, stream, dists, scal, out);
  hipLaunchKernelGGL(blurV_kernel, dim3(3136), dim3(256), 0, stream, s0, tmp);
  hipLaunchKernelGGL(blurH_kernel, dim3(3136), dim3(256), 0, stream, tmp, out);
}

// Round 2
// 1234.190 us; speedup vs baseline: 1.3661x; 1.3661x over previous
//
#include <hip/hip_runtime.h>
#include <hip/hip_bf16.h>

typedef __attribute__((ext_vector_type(4))) float f32x4;
typedef __attribute__((ext_vector_type(8))) short short8;
typedef __attribute__((ext_vector_type(4))) unsigned short u16x4;
typedef __attribute__((ext_vector_type(2))) unsigned short u16x2;

#define M_ROWS 12544   // 16*28*28
#define N_MEM  16384
#define K_DIM  1536

__device__ __forceinline__ float bf2f(unsigned short u) {
  return __uint_as_float(((unsigned)u) << 16);
}
__device__ __forceinline__ unsigned short f2bf(float f) {
  unsigned u = __float_as_uint(f);
  u += 0x7FFF + ((u >> 16) & 1);   // RNE
  return (unsigned short)(u >> 16);
}

// ---------------- Kernel 1a: avg_pool3 of f2 -> emb[:, 0:512] (bf16)
// grid (4 sq, 8 cb, 16 b); each block: 7 rows (196 positions) x 64 channels.
// Phase 1: lanes over spatial (coalesced reads), pooled bf16 -> LDS tile.
// Phase 2: transposed write-out, lanes over channels (coalesced 128B stores).
__global__ __launch_bounds__(256) void pool2_kernel(
    const float* __restrict__ f2, unsigned short* __restrict__ emb)
{
  int sq = blockIdx.x, cb = blockIdx.y, b = blockIdx.z;
  int h0 = sq * 7;
  __shared__ unsigned short tile[196][66];
  const float* base = f2 + ((size_t)b * 512 + cb * 64) * 784;
  #pragma unroll 2
  for (int i = 0; i < 49; ++i) {
    int idx = i * 256 + threadIdx.x;        // 0..12543 = 64ch * 196pos
    int cl = idx / 196;
    int p = idx - cl * 196;                 // 0..195
    int hr = p / 28;
    int w = p - hr * 28;
    int h = h0 + hr;
    const float* plane = base + (size_t)cl * 784;
    float v = 0.f;
    #pragma unroll
    for (int dh = -1; dh <= 1; ++dh) {
      int hh = h + dh; if (hh < 0 || hh > 27) continue;
      #pragma unroll
      for (int dw = -1; dw <= 1; ++dw) {
        int ww = w + dw; if (ww < 0 || ww > 27) continue;
        v += plane[hh * 28 + ww];
      }
    }
    tile[p][cl] = f2bf(v * (1.f / 9.f));
  }
  __syncthreads();
  #pragma unroll 2
  for (int i = 0; i < 49; ++i) {
    int idx = i * 256 + threadIdx.x;
    int s = idx >> 6, c = idx & 63;
    int r = b * 784 + h0 * 28 + s;
    emb[(size_t)r * K_DIM + cb * 64 + c] = tile[s][c];
  }
}

// ---------------- Kernel 1b: avg_pool3 of f3 + 2x nearest upsample -> emb[:, 512:1536]
// grid (16 cb, 16 b); each block: 14x14 pooled x 64 channels, written to 28x28.
__global__ __launch_bounds__(256) void pool3_kernel(
    const float* __restrict__ f3, unsigned short* __restrict__ emb)
{
  int cb = blockIdx.x, b = blockIdx.y;
  __shared__ unsigned short tile[196][66];
  const float* base = f3 + ((size_t)b * 1024 + cb * 64) * 196;
  #pragma unroll 2
  for (int i = 0; i < 49; ++i) {
    int idx = i * 256 + threadIdx.x;        // 64ch * 196pos (14x14)
    int cl = idx / 196;
    int p = idx - cl * 196;
    int h3 = p / 14;
    int w3 = p - h3 * 14;
    const float* plane = base + (size_t)cl * 196;
    float v = 0.f;
    #pragma unroll
    for (int dh = -1; dh <= 1; ++dh) {
      int hh = h3 + dh; if (hh < 0 || hh > 13) continue;
      #pragma unroll
      for (int dw = -1; dw <= 1; ++dw) {
        int ww = w3 + dw; if (ww < 0 || ww > 13) continue;
        v += plane[hh * 14 + ww];
      }
    }
    tile[p][cl] = f2bf(v * (1.f / 9.f));
  }
  __syncthreads();
  // 784 out positions x 64 ch, 2 channels per thread (u16x2): 98 iters
  #pragma unroll 2
  for (int i = 0; i < 98; ++i) {
    int idx = i * 256 + threadIdx.x;        // 784 * 32
    int s = idx >> 5;                       // 0..783
    int cp = (idx & 31) * 2;                // even channel index
    int h = s / 28, w = s - (s / 28) * 28;
    int p = (h >> 1) * 14 + (w >> 1);
    u16x2 v = *(const u16x2*)&tile[p][cp];
    *(u16x2*)&emb[(size_t)(b * 784 + s) * K_DIM + 512 + cb * 64 + cp] = v;
  }
}

// ---------------- Kernel 2: memory_bank -> bf16 + m2 (row sum of squares)
__global__ __launch_bounds__(256) void mbconv_kernel(
    const float* __restrict__ mb, unsigned short* __restrict__ mbb,
    float* __restrict__ m2)
{
  int wave = threadIdx.x >> 6, lane = threadIdx.x & 63;
  int row = blockIdx.x * 4 + wave;
  const float* src = mb + (size_t)row * K_DIM;
  unsigned short* dst = mbb + (size_t)row * K_DIM;
  float s = 0.f;
  #pragma unroll
  for (int c = 0; c < 6; ++c) {
    int off = c * 256 + lane * 4;
    float4 v = *(const float4*)(src + off);
    s += v.x * v.x + v.y * v.y + v.z * v.z + v.w * v.w;
    u16x4 o; o[0] = f2bf(v.x); o[1] = f2bf(v.y); o[2] = f2bf(v.z); o[3] = f2bf(v.w);
    *(u16x4*)(dst + off) = o;
  }
  #pragma unroll
  for (int d = 1; d < 64; d <<= 1) s += __shfl_xor(s, d);
  if (lane == 0) m2[row] = s;
}

// ---------------- Kernel 3: x2 (row sum of squares of bf16 embedding)
__global__ __launch_bounds__(256) void x2_kernel(
    const unsigned short* __restrict__ emb, float* __restrict__ x2)
{
  int wave = threadIdx.x >> 6, lane = threadIdx.x & 63;
  int row = blockIdx.x * 4 + wave;
  const unsigned short* src = emb + (size_t)row * K_DIM;
  float s = 0.f;
  #pragma unroll
  for (int c = 0; c < 3; ++c) {
    short8 v = *(const short8*)(src + c * 512 + lane * 8);
    #pragma unroll
    for (int j = 0; j < 8; ++j) {
      float f = bf2f((unsigned short)v[j]);
      s += f * f;
    }
  }
  #pragma unroll
  for (int d = 1; d < 64; d <<= 1) s += __shfl_xor(s, d);
  if (lane == 0) x2[row] = s;
}

// ---------------- Kernel 4: fused GEMM + min over columns
// grid: (N_MEM/128, M_ROWS/128) = (128, 98), block 256 (4 waves, 2x2)
__global__ __launch_bounds__(256) void gemm_min_kernel(
    const unsigned short* __restrict__ A,   // emb bf16 [12544][1536]
    const unsigned short* __restrict__ Bm,  // mb  bf16 [16384][1536]
    const float* __restrict__ m2,
    float* __restrict__ partial)
{
  __shared__ unsigned short lA[128 * 32];
  __shared__ unsigned short lB[128 * 32];
  const int tid = threadIdx.x;
  const int wave = tid >> 6, lane = tid & 63;
  const int bn = blockIdx.x, bm = blockIdx.y;
  const int rowBase = bm * 128, colBase = bn * 128;
  const int wr = wave >> 1, wc = wave & 1;

  f32x4 acc[4][4];
  #pragma unroll
  for (int i = 0; i < 4; ++i)
    #pragma unroll
    for (int j = 0; j < 4; ++j)
      acc[i][j] = (f32x4){0.f, 0.f, 0.f, 0.f};

  for (int kk = 0; kk < K_DIM; kk += 32) {
    #pragma unroll
    for (int i = 0; i < 2; ++i) {
      int e = i * 2048 + wave * 512 + lane * 8;
      int trow = e >> 5, tcol = e & 31;
      __builtin_amdgcn_global_load_lds(
          (const __attribute__((address_space(1))) void*)(A + (size_t)(rowBase + trow) * K_DIM + kk + tcol),
          (__attribute__((address_space(3))) void*)(lA + i * 2048 + wave * 512), 16, 0, 0);
      __builtin_amdgcn_global_load_lds(
          (const __attribute__((address_space(1))) void*)(Bm + (size_t)(colBase + trow) * K_DIM + kk + tcol),
          (__attribute__((address_space(3))) void*)(lB + i * 2048 + wave * 512), 16, 0, 0);
    }
    __syncthreads();
    short8 af[4], bf[4];
    #pragma unroll
    for (int f = 0; f < 4; ++f) {
      af[f] = *reinterpret_cast<const short8*>(&lA[(wr * 64 + f * 16 + (lane & 15)) * 32 + (lane >> 4) * 8]);
      bf[f] = *reinterpret_cast<const short8*>(&lB[(wc * 64 + f * 16 + (lane & 15)) * 32 + (lane >> 4) * 8]);
    }
    #pragma unroll
    for (int i = 0; i < 4; ++i)
      #pragma unroll
      for (int j = 0; j < 4; ++j)
        acc[i][j] = __builtin_amdgcn_mfma_f32_16x16x32_bf16(af[i], bf[j], acc[i][j], 0, 0, 0);
    __syncthreads();
  }

  float m2v[4];
  #pragma unroll
  for (int j = 0; j < 4; ++j)
    m2v[j] = m2[colBase + wc * 64 + j * 16 + (lane & 15)];
  const int q = lane >> 4;
  #pragma unroll
  for (int i = 0; i < 4; ++i) {
    #pragma unroll
    for (int v = 0; v < 4; ++v) {
      float mn = fminf(fminf(m2v[0] - 2.f * acc[i][0][v], m2v[1] - 2.f * acc[i][1][v]),
                       fminf(m2v[2] - 2.f * acc[i][2][v], m2v[3] - 2.f * acc[i][3][v]));
      #pragma unroll
      for (int d = 1; d < 16; d <<= 1) mn = fminf(mn, __shfl_xor(mn, d));
      if ((lane & 15) == 0) {
        int r = rowBase + wr * 64 + i * 16 + q * 4 + v;
        partial[(size_t)r * 256 + bn * 2 + wc] = mn;
      }
    }
  }
}

// ---------------- Kernel 5: reduce 256 partials per row -> s0
__global__ __launch_bounds__(256) void reduce_min_kernel(
    const float* __restrict__ partial, const float* __restrict__ x2,
    float* __restrict__ s0)
{
  int wave = threadIdx.x >> 6, lane = threadIdx.x & 63;
  int r = blockIdx.x * 4 + wave;
  float4 v4 = *(const float4*)&partial[(size_t)r * 256 + lane * 4];
  float mn = fminf(fminf(v4.x, v4.y), fminf(v4.z, v4.w));
  #pragma unroll
  for (int d = 1; d < 64; d <<= 1) mn = fminf(mn, __shfl_xor(mn, d));
  if (lane == 0) s0[r] = sqrtf(fmaxf(x2[r] + mn, 1e-12f));
}

// ---------------- Kernel 6: argmax over s0 (1024 threads)
__global__ __launch_bounds__(1024) void argmax_kernel(
    const float* __restrict__ s0, float* __restrict__ scal)
{
  __shared__ float sv[1024];
  __shared__ int si[1024];
  int tid = threadIdx.x;
  float best = -1e30f; int bi = 0x7fffffff;
  for (int i = tid; i < M_ROWS; i += 1024) {
    float v = s0[i];
    if (v > best) { best = v; bi = i; }
  }
  sv[tid] = best; si[tid] = bi;
  __syncthreads();
  for (int s = 512; s > 0; s >>= 1) {
    if (tid < s) {
      if (sv[tid + s] > sv[tid] || (sv[tid + s] == sv[tid] && si[tid + s] < si[tid])) {
        sv[tid] = sv[tid + s]; si[tid] = si[tid + s];
      }
    }
    __syncthreads();
  }
  if (tid == 0) { scal[0] = sv[0]; ((int*)scal)[1] = si[0]; }
}

// ---------------- Kernel 7: distances of the argmax row to all memory entries
__global__ __launch_bounds__(256) void rowdist_kernel(
    const unsigned short* __restrict__ emb, const unsigned short* __restrict__ mbb,
    const float* __restrict__ x2, const float* __restrict__ m2,
    const float* __restrict__ scal, float* __restrict__ dists)
{
  int wave = threadIdx.x >> 6, lane = threadIdx.x & 63;
  int m = blockIdx.x * 4 + wave;
  int ridx = ((const int*)scal)[1];
  const unsigned short* er = emb + (size_t)ridx * K_DIM;
  const unsigned short* mr = mbb + (size_t)m * K_DIM;
  float dot = 0.f;
  #pragma unroll
  for (int c = 0; c < 3; ++c) {
    short8 a = *(const short8*)(er + c * 512 + lane * 8);
    short8 b = *(const short8*)(mr + c * 512 + lane * 8);
    #pragma unroll
    for (int j = 0; j < 8; ++j)
      dot += bf2f((unsigned short)a[j]) * bf2f((unsigned short)b[j]);
  }
  #pragma unroll
  for (int d = 1; d < 64; d <<= 1) dot += __shfl_xor(dot, d);
  if (lane == 0)
    dists[m] = sqrtf(fmaxf(x2[ridx] + m2[m] - 2.f * dot, 1e-12f));
}

// ---------------- Kernel 8: top-9 smallest dists -> weights -> anomaly_score (1024 threads)
__global__ __launch_bounds__(1024) void topk_kernel(
    const float* __restrict__ dists, const float* __restrict__ scal,
    float* __restrict__ out)
{
  __shared__ float conf[9];
  __shared__ int chosen[9];
  __shared__ float swv[16];
  __shared__ int swi[16];
  int tid = threadIdx.x, lane = tid & 63, wave = tid >> 6;
  for (int t = 0; t < 9; ++t) {
    float best = 1e30f; int bi = 0x7fffffff;
    for (int i = tid; i < N_MEM; i += 1024) {
      bool skip = false;
      for (int u = 0; u < t; ++u) skip = skip || (chosen[u] == i);
      if (skip) continue;
      float v = dists[i];
      if (v < best || (v == best && i < bi)) { best = v; bi = i; }
    }
    #pragma unroll
    for (int d = 1; d < 64; d <<= 1) {
      float ov = __shfl_xor(best, d); int oi = __shfl_xor(bi, d);
      if (ov < best || (ov == best && oi < bi)) { best = ov; bi = oi; }
    }
    if (lane == 0) { swv[wave] = best; swi[wave] = bi; }
    __syncthreads();
    if (tid == 0) {
      float bb = swv[0]; int bbi = swi[0];
      for (int w = 1; w < 16; ++w)
        if (swv[w] < bb || (swv[w] == bb && swi[w] < bbi)) { bb = swv[w]; bbi = swi[w]; }
      conf[t] = bb; chosen[t] = bbi;
    }
    __syncthreads();
  }
  if (tid == 0) {
    float me = conf[0];
    for (int i = 1; i < 9; ++i) me = fmaxf(me, conf[i]);
    float den = 0.f;
    for (int i = 0; i < 9; ++i) den += expf(conf[i] - me);
    float w = 1.f - 1.f / den;
    out[802816] = w * scal[0];
  }
}

// ---------------- Kernels 9/10: 8x upsample + separable 33-tap gaussian blur (reflect)
__global__ __launch_bounds__(256) void blurV_kernel(
    const float* __restrict__ s0, float* __restrict__ tmp)
{
  __shared__ float g[33];
  __shared__ float ginv;
  int tid = threadIdx.x;
  if (tid < 33) { float x = (tid - 16) * 0.25f; g[tid] = expf(-0.5f * x * x); }
  __syncthreads();
  if (tid == 0) { float s = 0.f; for (int i = 0; i < 33; ++i) s += g[i]; ginv = 1.f / s; }
  __syncthreads();
  int gid = blockIdx.x * 256 + tid;       // 16*224*224
  int b = gid / 50176;
  int rem = gid - b * 50176;
  int y = rem / 224, x = rem - (rem / 224) * 224;
  const float* sb = s0 + b * 784;
  int sx = x >> 3;
  float acc = 0.f;
  for (int k = 0; k < 33; ++k) {
    int yy = y + k - 16;
    yy = (yy < 0) ? -yy : yy;
    yy = (yy > 223) ? 446 - yy : yy;
    acc += g[k] * sb[(yy >> 3) * 28 + sx];
  }
  tmp[gid] = acc * ginv;
}

__global__ __launch_bounds__(256) void blurH_kernel(
    const float* __restrict__ tmp, float* __restrict__ out)
{
  __shared__ float g[33];
  __shared__ float ginv;
  int tid = threadIdx.x;
  if (tid < 33) { float x = (tid - 16) * 0.25f; g[tid] = expf(-0.5f * x * x); }
  __syncthreads();
  if (tid == 0) { float s = 0.f; for (int i = 0; i < 33; ++i) s += g[i]; ginv = 1.f / s; }
  __syncthreads();
  int gid = blockIdx.x * 256 + tid;
  int b = gid / 50176;
  int rem = gid - b * 50176;
  int y = rem / 224, x = rem - (rem / 224) * 224;
  const float* tb = tmp + b * 50176 + y * 224;
  float acc = 0.f;
  for (int k = 0; k < 33; ++k) {
    int xx = x + k - 16;
    xx = (xx < 0) ? -xx : xx;
    xx = (xx > 223) ? 446 - xx : xx;
    acc += g[k] * tb[xx];
  }
  out[gid] = acc * ginv;
}

extern "C" void kernel_launch(void* const* d_in, const int* in_sizes, int n_in,
                              void* d_out, int out_size, void* d_ws, size_t ws_size,
                              hipStream_t stream) {
  const float* f2 = (const float*)d_in[0];
  const float* f3 = (const float*)d_in[1];
  const float* mb = (const float*)d_in[2];
  float* out = (float*)d_out;
  char* ws = (char*)d_ws;

  unsigned short* emb = (unsigned short*)(ws + 0);            // 38,535,168 B
  unsigned short* mbb = (unsigned short*)(ws + 38535168);     // 50,331,648 B
  float* x2      = (float*)(ws + 88866816);                   // 50,176 B
  float* m2      = (float*)(ws + 88916992);                   // 65,536 B
  float* partial = (float*)(ws + 88982528);                   // 12,845,056 B
  float* s0      = (float*)(ws + 101827584);                  // 50,176 B
  float* scal    = (float*)(ws + 101877760);                  // 64 B
  float* dists   = (float*)(ws + 101877824);                  // 65,536 B
  float* tmp     = (float*)(ws + 101943360);                  // 3,211,264 B

  hipLaunchKernelGGL(pool2_kernel, dim3(4, 8, 16), dim3(256), 0, stream, f2, emb);
  hipLaunchKernelGGL(pool3_kernel, dim3(16, 16), dim3(256), 0, stream, f3, emb);
  hipLaunchKernelGGL(mbconv_kernel, dim3(4096), dim3(256), 0, stream, mb, mbb, m2);
  hipLaunchKernelGGL(x2_kernel, dim3(3136), dim3(256), 0, stream, emb, x2);
  hipLaunchKernelGGL(gemm_min_kernel, dim3(128, 98), dim3(256), 0, stream, emb, mbb, m2, partial);
  hipLaunchKernelGGL(reduce_min_kernel, dim3(3136), dim3(256), 0, stream, partial, x2, s0);
  hipLaunchKernelGGL(argmax_kernel, dim3(1), dim3(1024), 0, stream, s0, scal);
  hipLaunchKernelGGL(rowdist_kernel, dim3(4096), dim3(256), 0, stream, emb, mbb, x2, m2, scal, dists);
  hipLaunchKernelGGL(topk_kernel, dim3(1), dim3(1024), 0, stream, dists, scal, out);
  hipLaunchKernelGGL(blurV_kernel, dim3(3136), dim3(256), 0, stream, s0, tmp);
  hipLaunchKernelGGL(blurH_kernel, dim3(3136), dim3(256), 0, stream, tmp, out);
}

// Round 3
// 1069.775 us; speedup vs baseline: 1.5761x; 1.1537x over previous
//
#include <hip/hip_runtime.h>
#include <hip/hip_bf16.h>

typedef __attribute__((ext_vector_type(4))) float f32x4;
typedef __attribute__((ext_vector_type(8))) short short8;
typedef __attribute__((ext_vector_type(4))) unsigned short u16x4;
typedef __attribute__((ext_vector_type(2))) unsigned short u16x2;

#define M_ROWS 12544   // 16*28*28
#define N_MEM  16384
#define K_DIM  1536
#define NT     48      // K_DIM / 32

__device__ __forceinline__ float bf2f(unsigned short u) {
  return __uint_as_float(((unsigned)u) << 16);
}
__device__ __forceinline__ unsigned short f2bf(float f) {
  unsigned u = __float_as_uint(f);
  u += 0x7FFF + ((u >> 16) & 1);   // RNE
  return (unsigned short)(u >> 16);
}

// ---------------- Kernel 1a: avg_pool3 of f2 -> emb[:, 0:512] (bf16)
__global__ __launch_bounds__(256) void pool2_kernel(
    const float* __restrict__ f2, unsigned short* __restrict__ emb)
{
  int sq = blockIdx.x, cb = blockIdx.y, b = blockIdx.z;
  int h0 = sq * 7;
  __shared__ unsigned short tile[196][66];
  const float* base = f2 + ((size_t)b * 512 + cb * 64) * 784;
  #pragma unroll 2
  for (int i = 0; i < 49; ++i) {
    int idx = i * 256 + threadIdx.x;        // 0..12543 = 64ch * 196pos
    int cl = idx / 196;
    int p = idx - cl * 196;                 // 0..195
    int hr = p / 28;
    int w = p - hr * 28;
    int h = h0 + hr;
    const float* plane = base + (size_t)cl * 784;
    float v = 0.f;
    #pragma unroll
    for (int dh = -1; dh <= 1; ++dh) {
      int hh = h + dh; if (hh < 0 || hh > 27) continue;
      #pragma unroll
      for (int dw = -1; dw <= 1; ++dw) {
        int ww = w + dw; if (ww < 0 || ww > 27) continue;
        v += plane[hh * 28 + ww];
      }
    }
    tile[p][cl] = f2bf(v * (1.f / 9.f));
  }
  __syncthreads();
  #pragma unroll 2
  for (int i = 0; i < 49; ++i) {
    int idx = i * 256 + threadIdx.x;
    int s = idx >> 6, c = idx & 63;
    int r = b * 784 + h0 * 28 + s;
    emb[(size_t)r * K_DIM + cb * 64 + c] = tile[s][c];
  }
}

// ---------------- Kernel 1b: avg_pool3 of f3 + 2x nearest upsample -> emb[:, 512:1536]
__global__ __launch_bounds__(256) void pool3_kernel(
    const float* __restrict__ f3, unsigned short* __restrict__ emb)
{
  int cb = blockIdx.x, b = blockIdx.y;
  __shared__ unsigned short tile[196][66];
  const float* base = f3 + ((size_t)b * 1024 + cb * 64) * 196;
  #pragma unroll 2
  for (int i = 0; i < 49; ++i) {
    int idx = i * 256 + threadIdx.x;        // 64ch * 196pos (14x14)
    int cl = idx / 196;
    int p = idx - cl * 196;
    int h3 = p / 14;
    int w3 = p - h3 * 14;
    const float* plane = base + (size_t)cl * 196;
    float v = 0.f;
    #pragma unroll
    for (int dh = -1; dh <= 1; ++dh) {
      int hh = h3 + dh; if (hh < 0 || hh > 13) continue;
      #pragma unroll
      for (int dw = -1; dw <= 1; ++dw) {
        int ww = w3 + dw; if (ww < 0 || ww > 13) continue;
        v += plane[hh * 14 + ww];
      }
    }
    tile[p][cl] = f2bf(v * (1.f / 9.f));
  }
  __syncthreads();
  #pragma unroll 2
  for (int i = 0; i < 98; ++i) {
    int idx = i * 256 + threadIdx.x;        // 784 * 32
    int s = idx >> 5;                       // 0..783
    int cp = (idx & 31) * 2;                // even channel index
    int h = s / 28, w = s - (s / 28) * 28;
    int p = (h >> 1) * 14 + (w >> 1);
    u16x2 v = *(const u16x2*)&tile[p][cp];
    *(u16x2*)&emb[(size_t)(b * 784 + s) * K_DIM + 512 + cb * 64 + cp] = v;
  }
}

// ---------------- Kernel 2: memory_bank -> bf16 + m2 (row sum of squares)
__global__ __launch_bounds__(256) void mbconv_kernel(
    const float* __restrict__ mb, unsigned short* __restrict__ mbb,
    float* __restrict__ m2)
{
  int wave = threadIdx.x >> 6, lane = threadIdx.x & 63;
  int row = blockIdx.x * 4 + wave;
  const float* src = mb + (size_t)row * K_DIM;
  unsigned short* dst = mbb + (size_t)row * K_DIM;
  float s = 0.f;
  #pragma unroll
  for (int c = 0; c < 6; ++c) {
    int off = c * 256 + lane * 4;
    float4 v = *(const float4*)(src + off);
    s += v.x * v.x + v.y * v.y + v.z * v.z + v.w * v.w;
    u16x4 o; o[0] = f2bf(v.x); o[1] = f2bf(v.y); o[2] = f2bf(v.z); o[3] = f2bf(v.w);
    *(u16x4*)(dst + off) = o;
  }
  #pragma unroll
  for (int d = 1; d < 64; d <<= 1) s += __shfl_xor(s, d);
  if (lane == 0) m2[row] = s;
}

// ---------------- Kernel 3: x2 (row sum of squares of bf16 embedding)
__global__ __launch_bounds__(256) void x2_kernel(
    const unsigned short* __restrict__ emb, float* __restrict__ x2)
{
  int wave = threadIdx.x >> 6, lane = threadIdx.x & 63;
  int row = blockIdx.x * 4 + wave;
  const unsigned short* src = emb + (size_t)row * K_DIM;
  float s = 0.f;
  #pragma unroll
  for (int c = 0; c < 3; ++c) {
    short8 v = *(const short8*)(src + c * 512 + lane * 8);
    #pragma unroll
    for (int j = 0; j < 8; ++j) {
      float f = bf2f((unsigned short)v[j]);
      s += f * f;
    }
  }
  #pragma unroll
  for (int d = 1; d < 64; d <<= 1) s += __shfl_xor(s, d);
  if (lane == 0) x2[row] = s;
}

// ---------------- Kernel 4: fused GEMM + min over columns
// 256x256 tile, 512 threads (8 waves, 2M x 4N), BK=32, triple-buffered LDS,
// counted vmcnt (never 0 in steady state), one barrier per K-tile,
// XOR-swizzled LDS (slot ^= (row>>1)&3 on 16B slots) on both write-src and read.
// partial[r*256 + bn*4 + wn] = min over that wave's 64 columns of (m2[m] - 2*dot)
__global__ __launch_bounds__(512, 2) void gemm_min_kernel(
    const unsigned short* __restrict__ A,   // emb bf16 [12544][1536]
    const unsigned short* __restrict__ Bm,  // mb  bf16 [16384][1536]
    const float* __restrict__ m2,
    float* __restrict__ partial)
{
  __shared__ unsigned short lds[49152];     // A: 3 x 8192 elts @0 ; B: 3 x 8192 elts @24576
  const int tid = threadIdx.x;
  const int wave = tid >> 6, lane = tid & 63;
  const int bn = blockIdx.x, bm = blockIdx.y;
  const int rowBase = bm * 256, colBase = bn * 256;
  const int wr = wave >> 2, wn = wave & 3;
  const int l15 = lane & 15, q = lane >> 4;
  // read-side swizzled within-row element offset (16B slot q XOR (row>>1)&3; row%16==l15)
  const int sq = (q ^ ((l15 >> 1) & 3)) << 3;

  // staging: thread covers row stRow (+128 for round 1), 16B slot (tid&3), swizzled source col
  const int stRow = tid >> 2;
  const int scol = ((tid & 3) ^ ((stRow >> 1) & 3)) << 3;   // (row+128)>>1 has same &3
  const unsigned short* gA0 = A + (size_t)(rowBase + stRow) * K_DIM + scol;
  const unsigned short* gA1 = gA0 + (size_t)128 * K_DIM;
  const unsigned short* gB0 = Bm + (size_t)(colBase + stRow) * K_DIM + scol;
  const unsigned short* gB1 = gB0 + (size_t)128 * K_DIM;
  const int ldsW = wave * 512;

  f32x4 acc[8][4];
  #pragma unroll
  for (int i = 0; i < 8; ++i)
    #pragma unroll
    for (int j = 0; j < 4; ++j)
      acc[i][j] = (f32x4){0.f, 0.f, 0.f, 0.f};

#define GLL(src, dstoff) __builtin_amdgcn_global_load_lds( \
    (const __attribute__((address_space(1))) void*)(src), \
    (__attribute__((address_space(3))) void*)(lds + (dstoff)), 16, 0, 0)

#define STAGE(slot, kk) do { \
    GLL(gA0 + (kk), (slot) * 8192 + ldsW); \
    GLL(gA1 + (kk), (slot) * 8192 + 4096 + ldsW); \
    GLL(gB0 + (kk), 24576 + (slot) * 8192 + ldsW); \
    GLL(gB1 + (kk), 24576 + (slot) * 8192 + 4096 + ldsW); \
  } while (0)

  // prologue: tiles 0 and 1 in flight; wait tile 0, keep tile 1's 4 loads outstanding
  STAGE(0, 0);
  STAGE(1, 32);
  asm volatile("s_waitcnt vmcnt(4)\n\ts_barrier" ::: "memory");

#define KTILE(slot, stslot, t) do { \
    if ((t) + 2 < NT) STAGE(stslot, ((t) + 2) * 32); \
    const unsigned short* Ab = lds + (slot) * 8192; \
    const unsigned short* Bb = lds + 24576 + (slot) * 8192; \
    short8 af[8], bf[4]; \
    _Pragma("unroll") \
    for (int j = 0; j < 4; ++j) \
      bf[j] = *(const short8*)(Bb + (wn * 64 + j * 16 + l15) * 32 + sq); \
    _Pragma("unroll") \
    for (int i = 0; i < 8; ++i) \
      af[i] = *(const short8*)(Ab + (wr * 128 + i * 16 + l15) * 32 + sq); \
    _Pragma("unroll") \
    for (int i = 0; i < 8; ++i) \
      _Pragma("unroll") \
      for (int j = 0; j < 4; ++j) \
        acc[i][j] = __builtin_amdgcn_mfma_f32_16x16x32_bf16(af[i], bf[j], acc[i][j], 0, 0, 0); \
    if ((t) + 2 < NT) { asm volatile("s_waitcnt vmcnt(4)\n\ts_barrier" ::: "memory"); } \
    else             { asm volatile("s_waitcnt vmcnt(0)\n\ts_barrier" ::: "memory"); } \
  } while (0)

  for (int tb = 0; tb < NT; tb += 3) {
    KTILE(0, 2, tb);
    KTILE(1, 0, tb + 1);
    KTILE(2, 1, tb + 2);
  }
#undef KTILE
#undef STAGE
#undef GLL

  // epilogue: val = m2[col] - 2*dot ; min over wave's 64 columns per row
  float m2v[4];
  #pragma unroll
  for (int j = 0; j < 4; ++j)
    m2v[j] = m2[colBase + wn * 64 + j * 16 + l15];
  #pragma unroll
  for (int i = 0; i < 8; ++i) {
    #pragma unroll
    for (int v = 0; v < 4; ++v) {
      float mn = fminf(fminf(m2v[0] - 2.f * acc[i][0][v], m2v[1] - 2.f * acc[i][1][v]),
                       fminf(m2v[2] - 2.f * acc[i][2][v], m2v[3] - 2.f * acc[i][3][v]));
      #pragma unroll
      for (int d = 1; d < 16; d <<= 1) mn = fminf(mn, __shfl_xor(mn, d));
      if (l15 == 0) {
        int r = rowBase + wr * 128 + i * 16 + q * 4 + v;
        partial[(size_t)r * 256 + bn * 4 + wn] = mn;
      }
    }
  }
}

// ---------------- Kernel 5: reduce 256 partials per row -> s0
__global__ __launch_bounds__(256) void reduce_min_kernel(
    const float* __restrict__ partial, const float* __restrict__ x2,
    float* __restrict__ s0)
{
  int wave = threadIdx.x >> 6, lane = threadIdx.x & 63;
  int r = blockIdx.x * 4 + wave;
  float4 v4 = *(const float4*)&partial[(size_t)r * 256 + lane * 4];
  float mn = fminf(fminf(v4.x, v4.y), fminf(v4.z, v4.w));
  #pragma unroll
  for (int d = 1; d < 64; d <<= 1) mn = fminf(mn, __shfl_xor(mn, d));
  if (lane == 0) s0[r] = sqrtf(fmaxf(x2[r] + mn, 1e-12f));
}

// ---------------- Kernel 6: argmax over s0 (1024 threads)
__global__ __launch_bounds__(1024) void argmax_kernel(
    const float* __restrict__ s0, float* __restrict__ scal)
{
  __shared__ float sv[1024];
  __shared__ int si[1024];
  int tid = threadIdx.x;
  float best = -1e30f; int bi = 0x7fffffff;
  for (int i = tid; i < M_ROWS; i += 1024) {
    float v = s0[i];
    if (v > best) { best = v; bi = i; }
  }
  sv[tid] = best; si[tid] = bi;
  __syncthreads();
  for (int s = 512; s > 0; s >>= 1) {
    if (tid < s) {
      if (sv[tid + s] > sv[tid] || (sv[tid + s] == sv[tid] && si[tid + s] < si[tid])) {
        sv[tid] = sv[tid + s]; si[tid] = si[tid + s];
      }
    }
    __syncthreads();
  }
  if (tid == 0) { scal[0] = sv[0]; ((int*)scal)[1] = si[0]; }
}

// ---------------- Kernel 7: distances of the argmax row to all memory entries
__global__ __launch_bounds__(256) void rowdist_kernel(
    const unsigned short* __restrict__ emb, const unsigned short* __restrict__ mbb,
    const float* __restrict__ x2, const float* __restrict__ m2,
    const float* __restrict__ scal, float* __restrict__ dists)
{
  int wave = threadIdx.x >> 6, lane = threadIdx.x & 63;
  int m = blockIdx.x * 4 + wave;
  int ridx = ((const int*)scal)[1];
  const unsigned short* er = emb + (size_t)ridx * K_DIM;
  const unsigned short* mr = mbb + (size_t)m * K_DIM;
  float dot = 0.f;
  #pragma unroll
  for (int c = 0; c < 3; ++c) {
    short8 a = *(const short8*)(er + c * 512 + lane * 8);
    short8 b = *(const short8*)(mr + c * 512 + lane * 8);
    #pragma unroll
    for (int j = 0; j < 8; ++j)
      dot += bf2f((unsigned short)a[j]) * bf2f((unsigned short)b[j]);
  }
  #pragma unroll
  for (int d = 1; d < 64; d <<= 1) dot += __shfl_xor(dot, d);
  if (lane == 0)
    dists[m] = sqrtf(fmaxf(x2[ridx] + m2[m] - 2.f * dot, 1e-12f));
}

// ---------------- Kernel 8: top-9 smallest dists -> weights -> anomaly_score (1024 threads)
__global__ __launch_bounds__(1024) void topk_kernel(
    const float* __restrict__ dists, const float* __restrict__ scal,
    float* __restrict__ out)
{
  __shared__ float conf[9];
  __shared__ int chosen[9];
  __shared__ float swv[16];
  __shared__ int swi[16];
  int tid = threadIdx.x, lane = tid & 63, wave = tid >> 6;
  for (int t = 0; t < 9; ++t) {
    float best = 1e30f; int bi = 0x7fffffff;
    for (int i = tid; i < N_MEM; i += 1024) {
      bool skip = false;
      for (int u = 0; u < t; ++u) skip = skip || (chosen[u] == i);
      if (skip) continue;
      float v = dists[i];
      if (v < best || (v == best && i < bi)) { best = v; bi = i; }
    }
    #pragma unroll
    for (int d = 1; d < 64; d <<= 1) {
      float ov = __shfl_xor(best, d); int oi = __shfl_xor(bi, d);
      if (ov < best || (ov == best && oi < bi)) { best = ov; bi = oi; }
    }
    if (lane == 0) { swv[wave] = best; swi[wave] = bi; }
    __syncthreads();
    if (tid == 0) {
      float bb = swv[0]; int bbi = swi[0];
      for (int w = 1; w < 16; ++w)
        if (swv[w] < bb || (swv[w] == bb && swi[w] < bbi)) { bb = swv[w]; bbi = swi[w]; }
      conf[t] = bb; chosen[t] = bbi;
    }
    __syncthreads();
  }
  if (tid == 0) {
    float me = conf[0];
    for (int i = 1; i < 9; ++i) me = fmaxf(me, conf[i]);
    float den = 0.f;
    for (int i = 0; i < 9; ++i) den += expf(conf[i] - me);
    float w = 1.f - 1.f / den;
    out[802816] = w * scal[0];
  }
}

// ---------------- Kernels 9/10: 8x upsample + separable 33-tap gaussian blur (reflect)
__global__ __launch_bounds__(256) void blurV_kernel(
    const float* __restrict__ s0, float* __restrict__ tmp)
{
  __shared__ float g[33];
  __shared__ float ginv;
  int tid = threadIdx.x;
  if (tid < 33) { float x = (tid - 16) * 0.25f; g[tid] = expf(-0.5f * x * x); }
  __syncthreads();
  if (tid == 0) { float s = 0.f; for (int i = 0; i < 33; ++i) s += g[i]; ginv = 1.f / s; }
  __syncthreads();
  int gid = blockIdx.x * 256 + tid;       // 16*224*224
  int b = gid / 50176;
  int rem = gid - b * 50176;
  int y = rem / 224, x = rem - (rem / 224) * 224;
  const float* sb = s0 + b * 784;
  int sx = x >> 3;
  float acc = 0.f;
  for (int k = 0; k < 33; ++k) {
    int yy = y + k - 16;
    yy = (yy < 0) ? -yy : yy;
    yy = (yy > 223) ? 446 - yy : yy;
    acc += g[k] * sb[(yy >> 3) * 28 + sx];
  }
  tmp[gid] = acc * ginv;
}

__global__ __launch_bounds__(256) void blurH_kernel(
    const float* __restrict__ tmp, float* __restrict__ out)
{
  __shared__ float g[33];
  __shared__ float ginv;
  int tid = threadIdx.x;
  if (tid < 33) { float x = (tid - 16) * 0.25f; g[tid] = expf(-0.5f * x * x); }
  __syncthreads();
  if (tid == 0) { float s = 0.f; for (int i = 0; i < 33; ++i) s += g[i]; ginv = 1.f / s; }
  __syncthreads();
  int gid = blockIdx.x * 256 + tid;
  int b = gid / 50176;
  int rem = gid - b * 50176;
  int y = rem / 224, x = rem - (rem / 224) * 224;
  const float* tb = tmp + b * 50176 + y * 224;
  float acc = 0.f;
  for (int k = 0; k < 33; ++k) {
    int xx = x + k - 16;
    xx = (xx < 0) ? -xx : xx;
    xx = (xx > 223) ? 446 - xx : xx;
    acc += g[k] * tb[xx];
  }
  out[gid] = acc * ginv;
}

extern "C" void kernel_launch(void* const* d_in, const int* in_sizes, int n_in,
                              void* d_out, int out_size, void* d_ws, size_t ws_size,
                              hipStream_t stream) {
  const float* f2 = (const float*)d_in[0];
  const float* f3 = (const float*)d_in[1];
  const float* mb = (const float*)d_in[2];
  float* out = (float*)d_out;
  char* ws = (char*)d_ws;

  unsigned short* emb = (unsigned short*)(ws + 0);            // 38,535,168 B
  unsigned short* mbb = (unsigned short*)(ws + 38535168);     // 50,331,648 B
  float* x2      = (float*)(ws + 88866816);                   // 50,176 B
  float* m2      = (float*)(ws + 88916992);                   // 65,536 B
  float* partial = (float*)(ws + 88982528);                   // 12,845,056 B
  float* s0      = (float*)(ws + 101827584);                  // 50,176 B
  float* scal    = (float*)(ws + 101877760);                  // 64 B
  float* dists   = (float*)(ws + 101877824);                  // 65,536 B
  float* tmp     = (float*)(ws + 101943360);                  // 3,211,264 B

  hipLaunchKernelGGL(pool2_kernel, dim3(4, 8, 16), dim3(256), 0, stream, f2, emb);
  hipLaunchKernelGGL(pool3_kernel, dim3(16, 16), dim3(256), 0, stream, f3, emb);
  hipLaunchKernelGGL(mbconv_kernel, dim3(4096), dim3(256), 0, stream, mb, mbb, m2);
  hipLaunchKernelGGL(x2_kernel, dim3(3136), dim3(256), 0, stream, emb, x2);
  hipLaunchKernelGGL(gemm_min_kernel, dim3(64, 49), dim3(512), 0, stream, emb, mbb, m2, partial);
  hipLaunchKernelGGL(reduce_min_kernel, dim3(3136), dim3(256), 0, stream, partial, x2, s0);
  hipLaunchKernelGGL(argmax_kernel, dim3(1), dim3(1024), 0, stream, s0, scal);
  hipLaunchKernelGGL(rowdist_kernel, dim3(4096), dim3(256), 0, stream, emb, mbb, x2, m2, scal, dists);
  hipLaunchKernelGGL(topk_kernel, dim3(1), dim3(1024), 0, stream, dists, scal, out);
  hipLaunchKernelGGL(blurV_kernel, dim3(3136), dim3(256), 0, stream, s0, tmp);
  hipLaunchKernelGGL(blurH_kernel, dim3(3136), dim3(256), 0, stream, tmp, out);
}